// Round 7
// baseline (501.054 us; speedup 1.0000x reference)
//
#include <hip/hip_runtime.h>
#include <hip/hip_fp16.h>

#define PTAB_STRIDE 64   // halves per row = 128 B
typedef float f2 __attribute__((ext_vector_type(2)));

__device__ __forceinline__ f2 fma2(f2 a, f2 b, f2 c) {
    return __builtin_elementwise_fma(a, b, c);
}

// ---------------------------------------------------------------------------
// Phase 1: ptab[v][h] = fp16( dot(emb[v,:], W_ih[h,:]) + b_ih[h] + b_hh[h] )
// k-chunk-outer, 8 rows per wave, NO prefetch ring (r5/r6 lesson: compiler
// collapses source-level rings). Latency hiding comes from occupancy:
// __launch_bounds__(256,4) -> VGPR<=128, LDS 38.4KB -> 4 blocks/CU -> 4
// waves/SIMD. Per chunk: 1 bcast ds_read_b128 (bank-disjoint, stride 1200B)
// + 8 W b128 loads (L1/L2-hot 60KB) + 16 v_pk_fma_f32.
// lane = (g = lane>>3 -> emb row, hq = lane&7 -> h-octet).
// ---------------------------------------------------------------------------
__global__ __launch_bounds__(256, 4) void ptab_kernel(
    const float* __restrict__ emb, const float* __restrict__ Wih,
    const float* __restrict__ bih, const float* __restrict__ bhh,
    __half* __restrict__ ptab)
{
    __shared__ __align__(16) float4 tile[4 * 600];   // 38400 B
    const int tid  = threadIdx.x;
    const int lane = tid & 63;
    const int wid  = tid >> 6;
    const int g    = lane >> 3;                      // emb row 0..7
    const int hq   = lane & 7;                       // h-octet 0..7

    const int wgid = blockIdx.x * 4 + wid;
    if (wgid >= 6250) return;                        // 50000 / 8 rows
    const int v0 = wgid * 8;

    // ---- stage this wave's 8 rows (2400 floats = 600 float4) into LDS ----
    const float4* src = (const float4*)(emb + (size_t)v0 * 300);
    float4* t = tile + wid * 600;
    #pragma unroll
    for (int j = 0; j < 9; ++j) t[lane + 64 * j] = src[lane + 64 * j];
    if (lane < 24) t[lane + 576] = src[lane + 576];
    // wave-private tile: same-wave DS ordering + compiler waitcnts suffice.

    // ---- W row pointers for this lane's 8 h's (clamped; h>=50 produces
    //      finite garbage written to ptab cols 50..63, never read by rnn) ----
    const int hb = hq * 8;
    const float* wr0 = Wih + min(hb + 0, 49) * 300;
    const float* wr1 = Wih + min(hb + 1, 49) * 300;
    const float* wr2 = Wih + min(hb + 2, 49) * 300;
    const float* wr3 = Wih + min(hb + 3, 49) * 300;
    const float* wr4 = Wih + min(hb + 4, 49) * 300;
    const float* wr5 = Wih + min(hb + 5, 49) * 300;
    const float* wr6 = Wih + min(hb + 6, 49) * 300;
    const float* wr7 = Wih + min(hb + 7, 49) * 300;

    f2 a0 = {0.f,0.f}, a1 = {0.f,0.f}, a2 = {0.f,0.f}, a3 = {0.f,0.f};
    f2 a4 = {0.f,0.f}, a5 = {0.f,0.f}, a6 = {0.f,0.f}, a7 = {0.f,0.f};

    const float4* erow = t + g * 75;

    #pragma unroll 2
    for (int kc = 0; kc < 75; ++kc) {
        float4 e  = erow[kc];                        // 8-addr bcast ds_read
        float4 w0 = *(const float4*)(wr0 + kc * 4);
        float4 w1 = *(const float4*)(wr1 + kc * 4);
        float4 w2 = *(const float4*)(wr2 + kc * 4);
        float4 w3 = *(const float4*)(wr3 + kc * 4);
        float4 w4 = *(const float4*)(wr4 + kc * 4);
        float4 w5 = *(const float4*)(wr5 + kc * 4);
        float4 w6 = *(const float4*)(wr6 + kc * 4);
        float4 w7 = *(const float4*)(wr7 + kc * 4);
        f2 elo = {e.x, e.y}, ehi = {e.z, e.w};
        a0 = fma2(elo, (f2){w0.x, w0.y}, a0);  a0 = fma2(ehi, (f2){w0.z, w0.w}, a0);
        a1 = fma2(elo, (f2){w1.x, w1.y}, a1);  a1 = fma2(ehi, (f2){w1.z, w1.w}, a1);
        a2 = fma2(elo, (f2){w2.x, w2.y}, a2);  a2 = fma2(ehi, (f2){w2.z, w2.w}, a2);
        a3 = fma2(elo, (f2){w3.x, w3.y}, a3);  a3 = fma2(ehi, (f2){w3.z, w3.w}, a3);
        a4 = fma2(elo, (f2){w4.x, w4.y}, a4);  a4 = fma2(ehi, (f2){w4.z, w4.w}, a4);
        a5 = fma2(elo, (f2){w5.x, w5.y}, a5);  a5 = fma2(ehi, (f2){w5.z, w5.w}, a5);
        a6 = fma2(elo, (f2){w6.x, w6.y}, a6);  a6 = fma2(ehi, (f2){w6.z, w6.w}, a6);
        a7 = fma2(elo, (f2){w7.x, w7.y}, a7);  a7 = fma2(ehi, (f2){w7.z, w7.w}, a7);
    }

    // ---- epilogue: bias + fp16 pack + one 16B store ----
    float o0 = a0.x + a0.y + bih[min(hb + 0, 49)] + bhh[min(hb + 0, 49)];
    float o1 = a1.x + a1.y + bih[min(hb + 1, 49)] + bhh[min(hb + 1, 49)];
    float o2 = a2.x + a2.y + bih[min(hb + 2, 49)] + bhh[min(hb + 2, 49)];
    float o3 = a3.x + a3.y + bih[min(hb + 3, 49)] + bhh[min(hb + 3, 49)];
    float o4 = a4.x + a4.y + bih[min(hb + 4, 49)] + bhh[min(hb + 4, 49)];
    float o5 = a5.x + a5.y + bih[min(hb + 5, 49)] + bhh[min(hb + 5, 49)];
    float o6 = a6.x + a6.y + bih[min(hb + 6, 49)] + bhh[min(hb + 6, 49)];
    float o7 = a7.x + a7.y + bih[min(hb + 7, 49)] + bhh[min(hb + 7, 49)];

    __half2 pk[4];
    pk[0] = __floats2half2_rn(o0, o1);
    pk[1] = __floats2half2_rn(o2, o3);
    pk[2] = __floats2half2_rn(o4, o5);
    pk[3] = __floats2half2_rn(o6, o7);
    *reinterpret_cast<float4*>(ptab + (size_t)(v0 + g) * PTAB_STRIDE + hb) =
        *reinterpret_cast<float4*>(pk);
}

// ---------------------------------------------------------------------------
// Phase 2: recurrence + head. One wave per batch element. x gathers now fp16
// (table 6.4 MB -> L2/L3-resident, 128B/row coalesced), 8 steps in flight.
// h broadcast: 1 ds_write_b32 + 12 ds_read_b128 + 1 ds_read_b64 (uniform).
// Dot: 25 v_pk_fma_f32. Biases pre-folded into ptab.
// ---------------------------------------------------------------------------
__global__ __launch_bounds__(64) void rnn_kernel(
    const int* __restrict__ tokens, const __half* __restrict__ ptab,
    const float* __restrict__ Whh,
    const float* __restrict__ Wfc, const float* __restrict__ bfc,
    float* __restrict__ out)
{
    __shared__ int   stok[544];
    __shared__ float hbuf[64];
    const int lane = threadIdx.x;
    const int b    = blockIdx.x;
    const int hc   = lane < 50 ? lane : 49;

    #pragma unroll
    for (int k = 0; k < 8; ++k)
        stok[lane + 64 * k] = tokens[b * 512 + lane + 64 * k];
    if (lane < 32) stok[512 + lane] = 0;     // pad: token 0 -> valid row
    __syncthreads();

    f2 whh2[25];
    #pragma unroll
    for (int j = 0; j < 25; ++j) {
        float2 w2 = *(const float2*)(Whh + hc * 50 + 2 * j);
        whh2[j].x = w2.x; whh2[j].y = w2.y;
    }

    float h = 0.f;

#define GATHER(T) ptab[(size_t)(T) * PTAB_STRIDE + lane]

    __half x0 = GATHER(stok[0]), x1 = GATHER(stok[1]);
    __half x2 = GATHER(stok[2]), x3 = GATHER(stok[3]);
    __half x4 = GATHER(stok[4]), x5 = GATHER(stok[5]);
    __half x6 = GATHER(stok[6]), x7 = GATHER(stok[7]);
    int k0 = stok[8],  k1 = stok[9],  k2 = stok[10], k3 = stok[11];
    int k4 = stok[12], k5 = stok[13], k6 = stok[14], k7 = stok[15];

#define RNN_STEP(XV)                                                        \
    {                                                                       \
        hbuf[lane] = h;                    /* ds_write_b32, in-order */     \
        const float4* hb4 = (const float4*)hbuf;                            \
        float4 h0 = hb4[0], h1 = hb4[1], h2 = hb4[2];                       \
        float4 h3 = hb4[3], h4 = hb4[4], h5 = hb4[5];                       \
        float4 h6 = hb4[6], h7 = hb4[7], h8 = hb4[8];                       \
        float4 h9 = hb4[9], h10 = hb4[10], h11 = hb4[11];                   \
        float2 h12 = *(const float2*)&hbuf[48];                             \
        f2 a0 = {0.f, 0.f}, a1 = {0.f, 0.f};                                \
        a0 = fma2((f2){h0.x,  h0.y},  whh2[0],  a0);                        \
        a1 = fma2((f2){h0.z,  h0.w},  whh2[1],  a1);                        \
        a0 = fma2((f2){h1.x,  h1.y},  whh2[2],  a0);                        \
        a1 = fma2((f2){h1.z,  h1.w},  whh2[3],  a1);                        \
        a0 = fma2((f2){h2.x,  h2.y},  whh2[4],  a0);                        \
        a1 = fma2((f2){h2.z,  h2.w},  whh2[5],  a1);                        \
        a0 = fma2((f2){h3.x,  h3.y},  whh2[6],  a0);                        \
        a1 = fma2((f2){h3.z,  h3.w},  whh2[7],  a1);                        \
        a0 = fma2((f2){h4.x,  h4.y},  whh2[8],  a0);                        \
        a1 = fma2((f2){h4.z,  h4.w},  whh2[9],  a1);                        \
        a0 = fma2((f2){h5.x,  h5.y},  whh2[10], a0);                        \
        a1 = fma2((f2){h5.z,  h5.w},  whh2[11], a1);                        \
        a0 = fma2((f2){h6.x,  h6.y},  whh2[12], a0);                        \
        a1 = fma2((f2){h6.z,  h6.w},  whh2[13], a1);                        \
        a0 = fma2((f2){h7.x,  h7.y},  whh2[14], a0);                        \
        a1 = fma2((f2){h7.z,  h7.w},  whh2[15], a1);                        \
        a0 = fma2((f2){h8.x,  h8.y},  whh2[16], a0);                        \
        a1 = fma2((f2){h8.z,  h8.w},  whh2[17], a1);                        \
        a0 = fma2((f2){h9.x,  h9.y},  whh2[18], a0);                        \
        a1 = fma2((f2){h9.z,  h9.w},  whh2[19], a1);                        \
        a0 = fma2((f2){h10.x, h10.y}, whh2[20], a0);                        \
        a1 = fma2((f2){h10.z, h10.w}, whh2[21], a1);                        \
        a0 = fma2((f2){h11.x, h11.y}, whh2[22], a0);                        \
        a1 = fma2((f2){h11.z, h11.w}, whh2[23], a1);                        \
        a0 = fma2((f2){h12.x, h12.y}, whh2[24], a0);                        \
        f2 sv = a0 + a1;                                                    \
        float a = __half2float(XV) + (sv.x + sv.y);                         \
        a = fminf(9.f, fmaxf(-9.f, a));                                     \
        float e = __expf(2.f * a);                                          \
        h = fmaf(-2.f, __builtin_amdgcn_rcpf(e + 1.f), 1.f);                \
    }

    for (int t = 0; t < 512; t += 8) {
        __half n0 = GATHER(k0), n1 = GATHER(k1), n2 = GATHER(k2), n3 = GATHER(k3);
        __half n4 = GATHER(k4), n5 = GATHER(k5), n6 = GATHER(k6), n7 = GATHER(k7);
        k0 = stok[t + 16]; k1 = stok[t + 17]; k2 = stok[t + 18]; k3 = stok[t + 19];
        k4 = stok[t + 20]; k5 = stok[t + 21]; k6 = stok[t + 22]; k7 = stok[t + 23];

        RNN_STEP(x0); RNN_STEP(x1); RNN_STEP(x2); RNN_STEP(x3);
        RNN_STEP(x4); RNN_STEP(x5); RNN_STEP(x6); RNN_STEP(x7);

        x0 = n0; x1 = n1; x2 = n2; x3 = n3;
        x4 = n4; x5 = n5; x6 = n6; x7 = n7;
    }
#undef RNN_STEP
#undef GATHER

    // ---- head: out[b][o] = sum_h h[h] * W_fc[o][h] + b_fc[o] ----
    float hv = (lane < 50) ? h : 0.f;
    #pragma unroll
    for (int o = 0; o < 4; ++o) {
        float w = (lane < 50) ? Wfc[o * 50 + lane] : 0.f;
        float p = hv * w;
        #pragma unroll
        for (int s = 32; s > 0; s >>= 1) p += __shfl_xor(p, s, 64);
        if (lane == 0) out[b * 4 + o] = p + bfc[o];
    }
}

extern "C" void kernel_launch(void* const* d_in, const int* in_sizes, int n_in,
                              void* d_out, int out_size, void* d_ws, size_t ws_size,
                              hipStream_t stream)
{
    const int*   tokens = (const int*)d_in[0];
    const float* emb    = (const float*)d_in[1];
    const float* Wih    = (const float*)d_in[2];
    const float* Whh    = (const float*)d_in[3];
    const float* bih    = (const float*)d_in[4];
    const float* bhh    = (const float*)d_in[5];
    const float* Wfc    = (const float*)d_in[6];
    const float* bfc    = (const float*)d_in[7];

    __half* ptab = (__half*)d_ws;        // 50000 * 64 * 2 B = 6.4 MB
    float*  outp = (float*)d_out;

    ptab_kernel<<<1563, 256, 0, stream>>>(emb, Wih, bih, bhh, ptab);
    rnn_kernel<<<256, 64, 0, stream>>>(tokens, ptab, Whh, Wfc, bfc, outp);
}

// Round 8
// 189.280 us; speedup vs baseline: 2.6472x; 2.6472x over previous
//
#include <hip/hip_runtime.h>
#include <hip/hip_fp16.h>

#define PTAB_STRIDE 64   // halves per row = 128 B

typedef float  f32x4 __attribute__((ext_vector_type(4)));
typedef _Float16 half8 __attribute__((ext_vector_type(8)));
typedef _Float16 h2    __attribute__((ext_vector_type(2)));

__device__ __forceinline__ h2 u2h2(unsigned int u) {
    union { unsigned int u; h2 h; } c; c.u = u; return c.h;
}

__device__ __forceinline__ float fdot2x(h2 a, h2 b, float c) {
#if __has_builtin(__builtin_amdgcn_fdot2)
    return __builtin_amdgcn_fdot2(a, b, c, false);
#else
    return c + (float)a[0] * (float)b[0] + (float)a[1] * (float)b[1];
#endif
}

// ---------------------------------------------------------------------------
// Kernel 0: pack B-fragments (W^T, fp16, zero-padded to K=320 x N=64) in the
// exact mfma_f32_16x16x32_f16 per-lane layout, + fused bias table.
// Block st = (s,t): s = K-step 0..9, t = N-tile 0..3. Lane l holds 8 halves:
// n = 16*t + (l&15), k = 32*s + 8*(l>>4) + j.  Block 40 writes bias64.
// ---------------------------------------------------------------------------
__global__ __launch_bounds__(64) void prep_kernel(
    const float* __restrict__ Wih, const float* __restrict__ bih,
    const float* __restrict__ bhh, __half* __restrict__ Bfrag,
    float* __restrict__ bias64)
{
    const int lane = threadIdx.x;
    const int st   = blockIdx.x;
    if (st == 40) {
        if (lane < 64) bias64[lane] = (lane < 50) ? bih[lane] + bhh[lane] : 0.f;
        return;
    }
    const int s  = st >> 2, t = st & 3;
    const int n  = 16 * t + (lane & 15);
    const int kb = lane >> 4;
    half8 v;
    #pragma unroll
    for (int j = 0; j < 8; ++j) {
        const int k = 32 * s + 8 * kb + j;
        float w = 0.f;
        if (n < 50 && k < 300) w = Wih[n * 300 + k];
        v[j] = (_Float16)w;
    }
    *reinterpret_cast<half8*>(Bfrag + ((size_t)st * 64 + lane) * 8) = v;
}

// ---------------------------------------------------------------------------
// Phase 1: ptab[v][h] = fp16( dot(emb[v,:], W_ih[h,:]) + b_ih + b_hh )
// One wave per 16 vocab rows, 4 accumulators (N-tiles of 16), 40 MFMAs.
// A-frag: lane l: row = l&15, k = 32s + 8*(l>>4) + j  -> 2 coalesced float4
// loads from emb + cvt to fp16. B-frag: one b128 load from Bfrag (L1-hot).
// The k-contraction is structurally over (lane-group, j), identical on both
// operands, so the mapping is self-consistent. C/D: col=lane&15 (=n),
// row=4*(lane>>4)+reg (=m)  [HW-verified m89 layout].
// ---------------------------------------------------------------------------
__global__ __launch_bounds__(64) void ptab_mfma(
    const float* __restrict__ emb, const __half* __restrict__ Bfrag,
    const float* __restrict__ bias64, __half* __restrict__ ptab)
{
    const int lane = threadIdx.x;
    const int v0   = blockIdx.x * 16;
    const int m    = lane & 15;
    const int kb   = lane >> 4;
    const float* Erow = emb + (size_t)(v0 + m) * 300;
    const half8* BF   = reinterpret_cast<const half8*>(Bfrag);

    f32x4 acc[4];
    #pragma unroll
    for (int t = 0; t < 4; ++t) acc[t] = (f32x4){0.f, 0.f, 0.f, 0.f};

    #pragma unroll
    for (int s = 0; s < 9; ++s) {
        const int k0 = 32 * s + 8 * kb;
        float4 p0 = *(const float4*)(Erow + k0);
        float4 p1 = *(const float4*)(Erow + k0 + 4);
        half8 a;
        a[0] = (_Float16)p0.x; a[1] = (_Float16)p0.y;
        a[2] = (_Float16)p0.z; a[3] = (_Float16)p0.w;
        a[4] = (_Float16)p1.x; a[5] = (_Float16)p1.y;
        a[6] = (_Float16)p1.z; a[7] = (_Float16)p1.w;
        #pragma unroll
        for (int t = 0; t < 4; ++t)
            acc[t] = __builtin_amdgcn_mfma_f32_16x16x32_f16(
                a, BF[(4 * s + t) * 64 + lane], acc[t], 0, 0, 0);
    }
    {   // tail K-step s=9: k = 288..319, valid only k < 300 (exec-masked)
        half8 a;
        #pragma unroll
        for (int j = 0; j < 8; ++j) {
            const int k = 288 + 8 * kb + j;
            float e = 0.f;
            if (k < 300) e = Erow[k];
            a[j] = (_Float16)e;
        }
        #pragma unroll
        for (int t = 0; t < 4; ++t)
            acc[t] = __builtin_amdgcn_mfma_f32_16x16x32_f16(
                a, BF[(36 + t) * 64 + lane], acc[t], 0, 0, 0);
    }

    // ---- epilogue: bias + fp16 store (cols 50..63 get exact 0 + 0 bias) ----
    const int nn = lane & 15;
    #pragma unroll
    for (int t = 0; t < 4; ++t) {
        const float bt = bias64[16 * t + nn];
        #pragma unroll
        for (int r = 0; r < 4; ++r)
            ptab[(size_t)(v0 + 4 * kb + r) * PTAB_STRIDE + 16 * t + nn] =
                (__half)(acc[t][r] + bt);
    }
}

// ---------------------------------------------------------------------------
// Phase 2: recurrence + head. TWO batch sequences per wave (latency hiding:
// batch B's compute overlaps batch A's LDS round trip). h kept as fp16 in
// LDS (50 halves -> 6 b128 + 1 b32 uniform broadcast reads), dot via
// v_dot2_f32_f16 (f32 accumulate). x gathers fp16, 8 steps in flight/batch.
// Biases pre-folded into ptab.
// ---------------------------------------------------------------------------
__global__ __launch_bounds__(64, 1) void rnn_kernel(
    const int* __restrict__ tokens, const __half* __restrict__ ptab,
    const float* __restrict__ Whh,
    const float* __restrict__ Wfc, const float* __restrict__ bfc,
    float* __restrict__ out)
{
    __shared__ int stokA[544], stokB[544];
    __shared__ __align__(16) unsigned int hbA_u[32], hbB_u[32];
    const int lane = threadIdx.x;
    const int bA   = blockIdx.x * 2;
    const int bB   = bA + 1;
    const int hc   = lane < 50 ? lane : 49;

    #pragma unroll
    for (int k = 0; k < 8; ++k) {
        stokA[lane + 64 * k] = tokens[bA * 512 + lane + 64 * k];
        stokB[lane + 64 * k] = tokens[bB * 512 + lane + 64 * k];
    }
    if (lane < 32) { stokA[512 + lane] = 0; stokB[512 + lane] = 0; }
    __syncthreads();

    // W_hh row for this lane as 25 packed fp16 pairs
    h2 wh[25];
    #pragma unroll
    for (int j = 0; j < 25; ++j) {
        float2 w2 = *(const float2*)(Whh + hc * 50 + 2 * j);
        wh[j] = (h2){(_Float16)w2.x, (_Float16)w2.y};
    }

    float hA = 0.f, hB = 0.f;

#define GA(T) ptab[(size_t)(T) * PTAB_STRIDE + lane]

    __half xA0 = GA(stokA[0]), xA1 = GA(stokA[1]), xA2 = GA(stokA[2]), xA3 = GA(stokA[3]);
    __half xA4 = GA(stokA[4]), xA5 = GA(stokA[5]), xA6 = GA(stokA[6]), xA7 = GA(stokA[7]);
    __half xB0 = GA(stokB[0]), xB1 = GA(stokB[1]), xB2 = GA(stokB[2]), xB3 = GA(stokB[3]);
    __half xB4 = GA(stokB[4]), xB5 = GA(stokB[5]), xB6 = GA(stokB[6]), xB7 = GA(stokB[7]);
    int kA0 = stokA[8],  kA1 = stokA[9],  kA2 = stokA[10], kA3 = stokA[11];
    int kA4 = stokA[12], kA5 = stokA[13], kA6 = stokA[14], kA7 = stokA[15];
    int kB0 = stokB[8],  kB1 = stokB[9],  kB2 = stokB[10], kB3 = stokB[11];
    int kB4 = stokB[12], kB5 = stokB[13], kB6 = stokB[14], kB7 = stokB[15];

#define DOT25(S0, S1, Q0, Q1, Q2, Q3, Q4, Q5, Q6)                         \
    S0 = fdot2x(u2h2(Q0.x), wh[0],  S0); S1 = fdot2x(u2h2(Q0.y), wh[1],  S1); \
    S0 = fdot2x(u2h2(Q0.z), wh[2],  S0); S1 = fdot2x(u2h2(Q0.w), wh[3],  S1); \
    S0 = fdot2x(u2h2(Q1.x), wh[4],  S0); S1 = fdot2x(u2h2(Q1.y), wh[5],  S1); \
    S0 = fdot2x(u2h2(Q1.z), wh[6],  S0); S1 = fdot2x(u2h2(Q1.w), wh[7],  S1); \
    S0 = fdot2x(u2h2(Q2.x), wh[8],  S0); S1 = fdot2x(u2h2(Q2.y), wh[9],  S1); \
    S0 = fdot2x(u2h2(Q2.z), wh[10], S0); S1 = fdot2x(u2h2(Q2.w), wh[11], S1); \
    S0 = fdot2x(u2h2(Q3.x), wh[12], S0); S1 = fdot2x(u2h2(Q3.y), wh[13], S1); \
    S0 = fdot2x(u2h2(Q3.z), wh[14], S0); S1 = fdot2x(u2h2(Q3.w), wh[15], S1); \
    S0 = fdot2x(u2h2(Q4.x), wh[16], S0); S1 = fdot2x(u2h2(Q4.y), wh[17], S1); \
    S0 = fdot2x(u2h2(Q4.z), wh[18], S0); S1 = fdot2x(u2h2(Q4.w), wh[19], S1); \
    S0 = fdot2x(u2h2(Q5.x), wh[20], S0); S1 = fdot2x(u2h2(Q5.y), wh[21], S1); \
    S0 = fdot2x(u2h2(Q5.z), wh[22], S0); S1 = fdot2x(u2h2(Q5.w), wh[23], S1); \
    S0 = fdot2x(u2h2(Q6),   wh[24], S0);

#define TANHSTEP(H, XV, S0, S1)                                           \
    {                                                                     \
        float a = (float)(XV) + (S0 + S1);                                \
        a = fminf(9.f, fmaxf(-9.f, a));                                   \
        float e = __expf(2.f * a);                                        \
        H = fmaf(-2.f, __builtin_amdgcn_rcpf(e + 1.f), 1.f);              \
    }

#define STEP2(XA, XB)                                                     \
    {                                                                     \
        ((_Float16*)hbA_u)[lane] = (_Float16)hA;                          \
        ((_Float16*)hbB_u)[lane] = (_Float16)hB;                          \
        asm volatile("" ::: "memory");                                    \
        const uint4* A4 = (const uint4*)hbA_u;                            \
        const uint4* B4 = (const uint4*)hbB_u;                            \
        uint4 qa0 = A4[0], qa1 = A4[1], qa2 = A4[2];                      \
        uint4 qa3 = A4[3], qa4 = A4[4], qa5 = A4[5];                      \
        unsigned int qa6 = hbA_u[24];                                     \
        uint4 qb0 = B4[0], qb1 = B4[1], qb2 = B4[2];                      \
        uint4 qb3 = B4[3], qb4 = B4[4], qb5 = B4[5];                      \
        unsigned int qb6 = hbB_u[24];                                     \
        float sA0 = 0.f, sA1 = 0.f, sB0 = 0.f, sB1 = 0.f;                 \
        DOT25(sA0, sA1, qa0, qa1, qa2, qa3, qa4, qa5, qa6)                \
        DOT25(sB0, sB1, qb0, qb1, qb2, qb3, qb4, qb5, qb6)                \
        TANHSTEP(hA, XA, sA0, sA1)                                        \
        TANHSTEP(hB, XB, sB0, sB1)                                        \
    }

    for (int t = 0; t < 512; t += 8) {
        __half nA0 = GA(kA0), nA1 = GA(kA1), nA2 = GA(kA2), nA3 = GA(kA3);
        __half nA4 = GA(kA4), nA5 = GA(kA5), nA6 = GA(kA6), nA7 = GA(kA7);
        __half nB0 = GA(kB0), nB1 = GA(kB1), nB2 = GA(kB2), nB3 = GA(kB3);
        __half nB4 = GA(kB4), nB5 = GA(kB5), nB6 = GA(kB6), nB7 = GA(kB7);
        kA0 = stokA[t + 16]; kA1 = stokA[t + 17]; kA2 = stokA[t + 18]; kA3 = stokA[t + 19];
        kA4 = stokA[t + 20]; kA5 = stokA[t + 21]; kA6 = stokA[t + 22]; kA7 = stokA[t + 23];
        kB0 = stokB[t + 16]; kB1 = stokB[t + 17]; kB2 = stokB[t + 18]; kB3 = stokB[t + 19];
        kB4 = stokB[t + 20]; kB5 = stokB[t + 21]; kB6 = stokB[t + 22]; kB7 = stokB[t + 23];

        STEP2(xA0, xB0); STEP2(xA1, xB1); STEP2(xA2, xB2); STEP2(xA3, xB3);
        STEP2(xA4, xB4); STEP2(xA5, xB5); STEP2(xA6, xB6); STEP2(xA7, xB7);

        xA0 = nA0; xA1 = nA1; xA2 = nA2; xA3 = nA3;
        xA4 = nA4; xA5 = nA5; xA6 = nA6; xA7 = nA7;
        xB0 = nB0; xB1 = nB1; xB2 = nB2; xB3 = nB3;
        xB4 = nB4; xB5 = nB5; xB6 = nB6; xB7 = nB7;
    }
#undef STEP2
#undef DOT25
#undef TANHSTEP
#undef GA

    // ---- head: out[b][o] = sum_h h[h] * W_fc[o][h] + b_fc[o], both batches ----
    float hvA = (lane < 50) ? hA : 0.f;
    float hvB = (lane < 50) ? hB : 0.f;
    #pragma unroll
    for (int o = 0; o < 4; ++o) {
        float w  = (lane < 50) ? Wfc[o * 50 + lane] : 0.f;
        float pA = hvA * w;
        float pB = hvB * w;
        #pragma unroll
        for (int s = 32; s > 0; s >>= 1) {
            pA += __shfl_xor(pA, s, 64);
            pB += __shfl_xor(pB, s, 64);
        }
        if (lane == 0) {
            out[bA * 4 + o] = pA + bfc[o];
            out[bB * 4 + o] = pB + bfc[o];
        }
    }
}

extern "C" void kernel_launch(void* const* d_in, const int* in_sizes, int n_in,
                              void* d_out, int out_size, void* d_ws, size_t ws_size,
                              hipStream_t stream)
{
    const int*   tokens = (const int*)d_in[0];
    const float* emb    = (const float*)d_in[1];
    const float* Wih    = (const float*)d_in[2];
    const float* Whh    = (const float*)d_in[3];
    const float* bih    = (const float*)d_in[4];
    const float* bhh    = (const float*)d_in[5];
    const float* Wfc    = (const float*)d_in[6];
    const float* bfc    = (const float*)d_in[7];

    char* ws = (char*)d_ws;
    __half* ptab   = (__half*)ws;                       // 6,400,000 B
    __half* Bfrag  = (__half*)(ws + 6400000);           //    40,960 B
    float*  bias64 = (float*)(ws + 6440960);            //       256 B
    float*  outp   = (float*)d_out;

    prep_kernel<<<41, 64, 0, stream>>>(Wih, bih, bhh, Bfrag, bias64);
    ptab_mfma<<<3125, 64, 0, stream>>>(emb, Bfrag, bias64, ptab);
    rnn_kernel<<<128, 64, 0, stream>>>(tokens, ptab, Whh, Wfc, bfc, outp);
}

// Round 9
// 110.550 us; speedup vs baseline: 4.5324x; 1.7122x over previous
//
#include <hip/hip_runtime.h>
#include <hip/hip_fp16.h>

#define PTAB_STRIDE 64   // halves per row = 128 B

typedef float    f32x4 __attribute__((ext_vector_type(4)));
typedef _Float16 half8 __attribute__((ext_vector_type(8)));
typedef _Float16 h2    __attribute__((ext_vector_type(2)));

__device__ __forceinline__ h2 u2h2(unsigned int u) {
    union { unsigned int u; h2 h; } c; c.u = u; return c.h;
}

__device__ __forceinline__ float fdot2x(h2 a, h2 b, float c) {
#if __has_builtin(__builtin_amdgcn_fdot2)
    return __builtin_amdgcn_fdot2(a, b, c, false);
#else
    return c + (float)a[0] * (float)b[0] + (float)a[1] * (float)b[1];
#endif
}

// ---------------------------------------------------------------------------
// Kernel 0: pack B-fragments (W^T, fp16, zero-padded to K=320 x N=64) in the
// exact mfma_f32_16x16x32_f16 per-lane layout, + fused bias table.
// Block st = (s,t): s = K-step 0..9, t = N-tile 0..3. Lane l holds 8 halves:
// n = 16*t + (l&15), k = 32*s + 8*(l>>4) + j.  Block 40 writes bias64.
// ---------------------------------------------------------------------------
__global__ __launch_bounds__(64) void prep_kernel(
    const float* __restrict__ Wih, const float* __restrict__ bih,
    const float* __restrict__ bhh, __half* __restrict__ Bfrag,
    float* __restrict__ bias64)
{
    const int lane = threadIdx.x;
    const int st   = blockIdx.x;
    if (st == 40) {
        if (lane < 64) bias64[lane] = (lane < 50) ? bih[lane] + bhh[lane] : 0.f;
        return;
    }
    const int s  = st >> 2, t = st & 3;
    const int n  = 16 * t + (lane & 15);
    const int kb = lane >> 4;
    half8 v;
    #pragma unroll
    for (int j = 0; j < 8; ++j) {
        const int k = 32 * s + 8 * kb + j;
        float w = 0.f;
        if (n < 50 && k < 300) w = Wih[n * 300 + k];
        v[j] = (_Float16)w;
    }
    *reinterpret_cast<half8*>(Bfrag + ((size_t)st * 64 + lane) * 8) = v;
}

// ---------------------------------------------------------------------------
// Phase 1: ptab[v][h] = fp16( dot(emb[v,:], W_ih[h,:]) + b_ih + b_hh )
// One wave per 16 vocab rows, 4 accumulators (N-tiles of 16), 40 MFMAs.
// A-frag from 2 coalesced float4 emb loads + cvt; B-frag b128 (L1-hot).
// C/D: col=lane&15 (=h), row=4*(lane>>4)+reg (=vocab row)  [m89 layout].
// ---------------------------------------------------------------------------
__global__ __launch_bounds__(64) void ptab_mfma(
    const float* __restrict__ emb, const __half* __restrict__ Bfrag,
    const float* __restrict__ bias64, __half* __restrict__ ptab)
{
    const int lane = threadIdx.x;
    const int v0   = blockIdx.x * 16;
    const int m    = lane & 15;
    const int kb   = lane >> 4;
    const float* Erow = emb + (size_t)(v0 + m) * 300;
    const half8* BF   = reinterpret_cast<const half8*>(Bfrag);

    f32x4 acc[4];
    #pragma unroll
    for (int t = 0; t < 4; ++t) acc[t] = (f32x4){0.f, 0.f, 0.f, 0.f};

    #pragma unroll
    for (int s = 0; s < 9; ++s) {
        const int k0 = 32 * s + 8 * kb;
        float4 p0 = *(const float4*)(Erow + k0);
        float4 p1 = *(const float4*)(Erow + k0 + 4);
        half8 a;
        a[0] = (_Float16)p0.x; a[1] = (_Float16)p0.y;
        a[2] = (_Float16)p0.z; a[3] = (_Float16)p0.w;
        a[4] = (_Float16)p1.x; a[5] = (_Float16)p1.y;
        a[6] = (_Float16)p1.z; a[7] = (_Float16)p1.w;
        #pragma unroll
        for (int t = 0; t < 4; ++t)
            acc[t] = __builtin_amdgcn_mfma_f32_16x16x32_f16(
                a, BF[(4 * s + t) * 64 + lane], acc[t], 0, 0, 0);
    }
    {   // tail K-step s=9: k = 288..319, valid only k < 300
        half8 a;
        #pragma unroll
        for (int j = 0; j < 8; ++j) {
            const int k = 288 + 8 * kb + j;
            float e = 0.f;
            if (k < 300) e = Erow[k];
            a[j] = (_Float16)e;
        }
        #pragma unroll
        for (int t = 0; t < 4; ++t)
            acc[t] = __builtin_amdgcn_mfma_f32_16x16x32_f16(
                a, BF[(36 + t) * 64 + lane], acc[t], 0, 0, 0);
    }

    const int nn = lane & 15;
    #pragma unroll
    for (int t = 0; t < 4; ++t) {
        const float bt = bias64[16 * t + nn];
        #pragma unroll
        for (int r = 0; r < 4; ++r)
            ptab[(size_t)(v0 + 4 * kb + r) * PTAB_STRIDE + 16 * t + nn] =
                (__half)(acc[t][r] + bt);
    }
}

// ---------------------------------------------------------------------------
// Phase 2: recurrence + head. ONE sequence per wave, 256 waves (1/CU).
// Lane l owns h[l] (fp16 in hbuf). Per step: 1 ds_write_b16 + 6 half8 +
// 1 h2 uniform broadcast reads + 25 v_dot2_f32_f16 (2 chains) + tanh.
// wh (25 packed fp16 pairs) is PINNED into VGPRs via asm "+v" so the
// allocator cannot rematerialize it inside the loop (round-8 lesson:
// VGPR=48 meant W_hh was re-loaded from global every step).
// x gathers prefetched 8 steps ahead. Biases pre-folded into ptab.
// ---------------------------------------------------------------------------
__global__ __launch_bounds__(64, 1) void rnn_kernel(
    const int* __restrict__ tokens, const __half* __restrict__ ptab,
    const float* __restrict__ Whh,
    const float* __restrict__ Wfc, const float* __restrict__ bfc,
    float* __restrict__ out)
{
    __shared__ int stok[544];
    __shared__ __align__(16) _Float16 hbuf[64];
    const int lane = threadIdx.x;
    const int b    = blockIdx.x;
    const int hc   = lane < 50 ? lane : 49;

    #pragma unroll
    for (int k = 0; k < 8; ++k)
        stok[lane + 64 * k] = tokens[b * 512 + lane + 64 * k];
    if (lane < 32) stok[512 + lane] = 0;     // pad: token 0 -> valid row
    __syncthreads();

    // W_hh row for this lane: 25 packed fp16 pairs, pinned in VGPRs.
    unsigned int wh_u[25];
    #pragma unroll
    for (int j = 0; j < 25; ++j) {
        float2 w2 = *(const float2*)(Whh + hc * 50 + 2 * j);
        union { h2 h; unsigned int u; } c;
        c.h = (h2){(_Float16)w2.x, (_Float16)w2.y};
        wh_u[j] = c.u;
    }
    #pragma unroll
    for (int j = 0; j < 25; ++j)
        asm volatile("" : "+v"(wh_u[j]));    // opaque def: must stay in VGPR

    float h = 0.f;

#define GA(T) ptab[(size_t)(T) * PTAB_STRIDE + lane]

    __half x0 = GA(stok[0]), x1 = GA(stok[1]), x2 = GA(stok[2]), x3 = GA(stok[3]);
    __half x4 = GA(stok[4]), x5 = GA(stok[5]), x6 = GA(stok[6]), x7 = GA(stok[7]);
    int k0 = stok[8],  k1 = stok[9],  k2 = stok[10], k3 = stok[11];
    int k4 = stok[12], k5 = stok[13], k6 = stok[14], k7 = stok[15];

#define SL(Q, i) __builtin_shufflevector(Q, Q, 2*(i), 2*(i)+1)
#define WH(j) u2h2(wh_u[j])

#define RNN_STEP(XV)                                                        \
    {                                                                       \
        hbuf[lane] = (_Float16)h;          /* ds_write_b16, in-order */     \
        const half8* H8 = (const half8*)hbuf;                               \
        half8 q0 = H8[0], q1 = H8[1], q2 = H8[2];                           \
        half8 q3 = H8[3], q4 = H8[4], q5 = H8[5];                           \
        h2 q6 = *(const h2*)(hbuf + 48);                                    \
        float s0 = 0.f, s1 = 0.f;                                           \
        s0 = fdot2x(SL(q0,0), WH(0),  s0); s1 = fdot2x(SL(q0,1), WH(1),  s1); \
        s0 = fdot2x(SL(q0,2), WH(2),  s0); s1 = fdot2x(SL(q0,3), WH(3),  s1); \
        s0 = fdot2x(SL(q1,0), WH(4),  s0); s1 = fdot2x(SL(q1,1), WH(5),  s1); \
        s0 = fdot2x(SL(q1,2), WH(6),  s0); s1 = fdot2x(SL(q1,3), WH(7),  s1); \
        s0 = fdot2x(SL(q2,0), WH(8),  s0); s1 = fdot2x(SL(q2,1), WH(9),  s1); \
        s0 = fdot2x(SL(q2,2), WH(10), s0); s1 = fdot2x(SL(q2,3), WH(11), s1); \
        s0 = fdot2x(SL(q3,0), WH(12), s0); s1 = fdot2x(SL(q3,1), WH(13), s1); \
        s0 = fdot2x(SL(q3,2), WH(14), s0); s1 = fdot2x(SL(q3,3), WH(15), s1); \
        s0 = fdot2x(SL(q4,0), WH(16), s0); s1 = fdot2x(SL(q4,1), WH(17), s1); \
        s0 = fdot2x(SL(q4,2), WH(18), s0); s1 = fdot2x(SL(q4,3), WH(19), s1); \
        s0 = fdot2x(SL(q5,0), WH(20), s0); s1 = fdot2x(SL(q5,1), WH(21), s1); \
        s0 = fdot2x(SL(q5,2), WH(22), s0); s1 = fdot2x(SL(q5,3), WH(23), s1); \
        s0 = fdot2x(q6,       WH(24), s0);                                  \
        float a = (float)(XV) + (s0 + s1);                                  \
        a = fminf(9.f, fmaxf(-9.f, a));                                     \
        float e = __expf(2.f * a);                                          \
        h = fmaf(-2.f, __builtin_amdgcn_rcpf(e + 1.f), 1.f);                \
    }

    for (int t = 0; t < 512; t += 8) {
        __half n0 = GA(k0), n1 = GA(k1), n2 = GA(k2), n3 = GA(k3);
        __half n4 = GA(k4), n5 = GA(k5), n6 = GA(k6), n7 = GA(k7);
        k0 = stok[t + 16]; k1 = stok[t + 17]; k2 = stok[t + 18]; k3 = stok[t + 19];
        k4 = stok[t + 20]; k5 = stok[t + 21]; k6 = stok[t + 22]; k7 = stok[t + 23];

        RNN_STEP(x0); RNN_STEP(x1); RNN_STEP(x2); RNN_STEP(x3);
        RNN_STEP(x4); RNN_STEP(x5); RNN_STEP(x6); RNN_STEP(x7);

        x0 = n0; x1 = n1; x2 = n2; x3 = n3;
        x4 = n4; x5 = n5; x6 = n6; x7 = n7;
    }
#undef RNN_STEP
#undef SL
#undef WH
#undef GA

    // ---- head: out[b][o] = sum_h h[h] * W_fc[o][h] + b_fc[o] ----
    float hv = (lane < 50) ? h : 0.f;
    #pragma unroll
    for (int o = 0; o < 4; ++o) {
        float w = (lane < 50) ? Wfc[o * 50 + lane] : 0.f;
        float p = hv * w;
        #pragma unroll
        for (int s = 32; s > 0; s >>= 1) p += __shfl_xor(p, s, 64);
        if (lane == 0) out[b * 4 + o] = p + bfc[o];
    }
}

extern "C" void kernel_launch(void* const* d_in, const int* in_sizes, int n_in,
                              void* d_out, int out_size, void* d_ws, size_t ws_size,
                              hipStream_t stream)
{
    const int*   tokens = (const int*)d_in[0];
    const float* emb    = (const float*)d_in[1];
    const float* Wih    = (const float*)d_in[2];
    const float* Whh    = (const float*)d_in[3];
    const float* bih    = (const float*)d_in[4];
    const float* bhh    = (const float*)d_in[5];
    const float* Wfc    = (const float*)d_in[6];
    const float* bfc    = (const float*)d_in[7];

    char* ws = (char*)d_ws;
    __half* ptab   = (__half*)ws;                       // 6,400,000 B
    __half* Bfrag  = (__half*)(ws + 6400000);           //    40,960 B
    float*  bias64 = (float*)(ws + 6440960);            //       256 B
    float*  outp   = (float*)d_out;

    prep_kernel<<<41, 64, 0, stream>>>(Wih, bih, bhh, Bfrag, bias64);
    ptab_mfma<<<3125, 64, 0, stream>>>(emb, Bfrag, bias64, ptab);
    rnn_kernel<<<256, 64, 0, stream>>>(tokens, ptab, Whh, Wfc, bfc, outp);
}